// Round 1
// 521.628 us; speedup vs baseline: 1.1790x; 1.1790x over previous
//
#include <hip/hip_runtime.h>
#include <math.h>

typedef int v4i  __attribute__((ext_vector_type(4)));
typedef int v16i __attribute__((ext_vector_type(16)));
typedef short v8s __attribute__((ext_vector_type(8)));
typedef float v16f __attribute__((ext_vector_type(16)));

#define N_IMG 32
#define CIN   256
#define CMID  128
#define COUT  512
#define HWP   3136
#define W58   58
#define PLANE_Q 3456            // 27 tiles of 128 (3364 valid padded positions + tail)
#define CBSTRIDE (PLANE_Q*16)   // 55296 bytes per 16-channel plane
#define IMGSTRIDE (8*CBSTRIDE)  // 442368 bytes per image (128 ch)
#define BSROW 248               // staged halo rows (246 used)
#define GUARD 16384
#define BN_EPS_F 1e-3f
#define ALPHA_F  10.0f
#define ARELU_S  25.5f

// ---------------- workspace layout (float units unless noted) ----------------
#define OFF_WQ1   0            // 32768 fp32 (conv1 folded weights fp32)
#define OFF_WF2   32768        // 147456 fp32 (folded w2, temp)
#define OFF_WF3   180224       // 65536 fp32 (folded w3, temp)
#define OFF_BQ1   245760
#define OFF_BQ2   245888
#define OFF_BQ3   246016
#define OFF_MAX   246528       // 3 uints
#define OFF_Q2    246536       // 128 ints
#define OFF_Q3    246664       // 512 ints
#define OFF_WQ2I  247296       // i8 [9][128][128] = 147456 B (36864 floats)
#define OFF_WQ3I  284160       // i8 [512][128]    = 65536 B  (16384 floats)
#define OFF_WBF1  300544       // bf16 [32 kb][128 m][8] = 64 KB (reuses old act1f region)
// byte offsets for i8 activation planes (layout unchanged from verified baseline):
#define ACT1Q_GUARD_B 52582400u
#define ACT1Q_B       (ACT1Q_GUARD_B + GUARD)
#define ACT2Q_B       (ACT1Q_B + (unsigned)(N_IMG*IMGSTRIDE) + GUARD)

__device__ __forceinline__ void async16(const char* g, char* l) {
    __builtin_amdgcn_global_load_lds((const __attribute__((address_space(1))) void*)g,
                                     (__attribute__((address_space(3))) void*)l, 16, 0, 0);
}

__device__ __forceinline__ unsigned bf16rne(float f) {
    unsigned u = __float_as_uint(f);
    return (u + 0x7fffu + ((u >> 16) & 1u)) >> 16;
}
__device__ __forceinline__ float bfval(unsigned h) {
    return __uint_as_float(h << 16);
}

// ---------------- fold BN into weights + track |max| ----------------
__global__ __launch_bounds__(256) void fold_max_kernel(
    const float* __restrict__ w, const float* __restrict__ g,
    const float* __restrict__ v, float* __restrict__ wf,
    unsigned int* __restrict__ maxbits, int inner, int total)
{
    __shared__ float smax[256];
    float m = 0.f;
    for (int i = blockIdx.x * 256 + threadIdx.x; i < total; i += gridDim.x * 256) {
        int o = i / inner;
        float sc = g[o] / sqrtf(v[o] + BN_EPS_F);
        float val = w[i] * sc;
        wf[i] = val;
        m = fmaxf(m, fabsf(val));
    }
    smax[threadIdx.x] = m;
    __syncthreads();
    for (int s = 128; s > 0; s >>= 1) {
        if (threadIdx.x < s) smax[threadIdx.x] = fmaxf(smax[threadIdx.x], smax[threadIdx.x + s]);
        __syncthreads();
    }
    if (threadIdx.x == 0) atomicMax(maxbits, __float_as_uint(smax[0]));
}

// ---------------- quantize conv1 weights -> integer-valued bf16, MFMA layout ----------------
// wbf[(c>>3)*128*8 + m*8 + (c&7)] = bf16((float)k), k = rint(wf*s) in [-127,127] (exact in bf16)
__global__ __launch_bounds__(256) void quant_w1_bf16_kernel(
    const float* __restrict__ wf1, const unsigned int* __restrict__ maxbits,
    unsigned short* __restrict__ wbf)
{
    int i = blockIdx.x * 256 + threadIdx.x;   // 32768 total
    float s = 127.0f / fmaxf(__uint_as_float(*maxbits), 1e-8f);
    int kb = i >> 10, rem = i & 1023;
    int m = rem >> 3, j = rem & 7;
    int c = kb * 8 + j;
    float k = rintf(wf1[m * CIN + c] * s);
    wbf[i] = (unsigned short)(__float_as_uint(k) >> 16);
}

// ---------------- quantize w2 to i8, layout [tap][m][c], plus Q2[m]=sum q ----------------
__global__ __launch_bounds__(256) void quant_w2_kernel(
    const float* __restrict__ wf2, const unsigned int* __restrict__ maxw,
    char* __restrict__ wq2i, int* __restrict__ Q2)
{
    __shared__ int red[256];
    int m = blockIdx.x;
    float s = 127.0f / fmaxf(__uint_as_float(maxw[1]), 1e-8f);
    int sum = 0;
    for (int idx = threadIdx.x; idx < CMID * 9; idx += 256) {
        int c = idx / 9, tap = idx - c * 9;
        int q = (int)rintf(wf2[(size_t)m * (CMID * 9) + idx] * s);
        wq2i[(size_t)tap * (CMID * CMID) + m * CMID + c] = (char)q;
        sum += q;
    }
    red[threadIdx.x] = sum;
    __syncthreads();
    for (int st = 128; st > 0; st >>= 1) {
        if (threadIdx.x < st) red[threadIdx.x] += red[threadIdx.x + st];
        __syncthreads();
    }
    if (threadIdx.x == 0) Q2[m] = red[0];
}

// ---------------- quantize w3 to i8, layout [m][c], plus Q3[m] ----------------
__global__ __launch_bounds__(128) void quant_w3_kernel(
    const float* __restrict__ wf3, const unsigned int* __restrict__ maxw,
    char* __restrict__ wq3i, int* __restrict__ Q3)
{
    __shared__ int red[128];
    int m = blockIdx.x, c = threadIdx.x;
    float s = 127.0f / fmaxf(__uint_as_float(maxw[2]), 1e-8f);
    int q = (int)rintf(wf3[(size_t)m * CMID + c] * s);
    wq3i[(size_t)m * CMID + c] = (char)q;
    red[c] = q;
    __syncthreads();
    for (int st = 64; st > 0; st >>= 1) {
        if (c < st) red[c] += red[c + st];
        __syncthreads();
    }
    if (c == 0) Q3[m] = red[0];
}

// ---------------- fold + quantize bias ----------------
__global__ __launch_bounds__(512) void fold_bias_kernel(
    const float* __restrict__ b, const float* __restrict__ g,
    const float* __restrict__ be, const float* __restrict__ m,
    const float* __restrict__ v, float* __restrict__ bq, int n)
{
    __shared__ float red[512];
    int t = threadIdx.x;
    float val = 0.f;
    if (t < n) {
        float sc = g[t] / sqrtf(v[t] + BN_EPS_F);
        val = (b[t] - m[t]) * sc + be[t];
    }
    red[t] = (t < n) ? fabsf(val) : 0.f;
    __syncthreads();
    for (int s = 256; s > 0; s >>= 1) {
        if (t < s) red[t] = fmaxf(red[t], red[t + s]);
        __syncthreads();
    }
    float mx = fmaxf(red[0], 1e-8f);
    float s = 32767.0f / mx;
    if (t < n) bq[t] = rintf(val * s) / s;
}

// ---------------- conv1: 1x1 bf16 MFMA (3-way split-fp32) + qrelu -> packed i8 ----------------
// W as exact-integer bf16; x split x = hi + mid + lo (bf16 each), 3 accumulating MFMA passes.
// Epilogue fuses dequant + qrelu + transpose-pack into the padded [cb][q][16] i8 layout
// (repack_kernel eliminated; border q masked so memset pad halo survives for conv2).
__global__ __launch_bounds__(256) void conv1_bf16_kernel(
    const float* __restrict__ X, const unsigned short* __restrict__ Wbf,
    const unsigned int* __restrict__ maxw, const float* __restrict__ bq1,
    char* __restrict__ act1q)
{
    __shared__ char lds[65536];
    char* As = lds;             // [8 kb][128 m][16]  bf16 integer weights
    char* Bh = lds + 16384;     // [8 kb][128 q][16]  x hi
    char* Bm = lds + 32768;     //                    x mid
    char* Bl = lds + 49152;     //                    x lo
    const int tid = threadIdx.x;
    const int n  = blockIdx.z;
    const int q0 = blockIdx.x * 128;
    const int lane = tid & 63, wid = tid >> 6;
    const int lo = lane & 31, hi = lane >> 5;
    const int wm = wid >> 1, wn = wid & 1;
    const float* Xn = X + (size_t)n * CIN * HWP;

    v16f acc[2][2] = {};

    for (int kc = 0; kc < 4; kc++) {          // 4 chunks of 64 input channels
        __syncthreads();                      // prior chunk's LDS reads done
        const char* wsrc = (const char*)Wbf + kc * 16384;
#pragma unroll
        for (int i = 0; i < 4; i++)
            async16(wsrc + (i * 256 + tid) * 16, As + (i * 256 + tid) * 16);
#pragma unroll
        for (int i = 0; i < 4; i++) {
            int e = i * 256 + tid;            // (kb, qi) entry: one 16B row of 8 channels
            int kb = e >> 7, qi = e & 127;
            int q = q0 + qi;
            int y = q / W58, xx = q - y * W58;
            int p = (y - 1) * 56 + (xx - 1);  // border q: clamp; garbage col masked at store
            p = p < 0 ? 0 : (p > HWP - 1 ? HWP - 1 : p);
            const float* src = Xn + (size_t)(kc * 64 + kb * 8) * HWP + p;
            float v[8];
#pragma unroll
            for (int j = 0; j < 8; j++) v[j] = src[j * HWP];
            unsigned ph[4], pm_[4], pl[4];
#pragma unroll
            for (int jj = 0; jj < 4; jj++) {
                float a0 = v[2 * jj], a1 = v[2 * jj + 1];
                unsigned h0 = bf16rne(a0), h1 = bf16rne(a1);
                float r0 = a0 - bfval(h0), r1 = a1 - bfval(h1);
                unsigned m0_ = bf16rne(r0), m1_ = bf16rne(r1);
                float t0 = r0 - bfval(m0_), t1 = r1 - bfval(m1_);
                unsigned l0 = bf16rne(t0), l1 = bf16rne(t1);
                ph[jj]  = h0 | (h1 << 16);
                pm_[jj] = m0_ | (m1_ << 16);
                pl[jj]  = l0 | (l1 << 16);
            }
            int off = (kb * 128 + qi) * 16;
            *(uint4*)(Bh + off) = make_uint4(ph[0], ph[1], ph[2], ph[3]);
            *(uint4*)(Bm + off) = make_uint4(pm_[0], pm_[1], pm_[2], pm_[3]);
            *(uint4*)(Bl + off) = make_uint4(pl[0], pl[1], pl[2], pl[3]);
        }
        __syncthreads();                      // staging visible (barrier drains LDS-DMA)
#pragma unroll
        for (int pass = 0; pass < 3; pass++) {
            const char* Bp = (pass == 0) ? Bh : ((pass == 1) ? Bm : Bl);
#pragma unroll
            for (int ks = 0; ks < 4; ks++) {
                v8s a[2], b[2];
#pragma unroll
                for (int s = 0; s < 2; s++)
                    a[s] = *(const v8s*)(As + ((ks * 2 + hi) * 128 + wm * 64 + s * 32 + lo) * 16);
#pragma unroll
                for (int t = 0; t < 2; t++)
                    b[t] = *(const v8s*)(Bp + ((ks * 2 + hi) * 128 + wn * 64 + t * 32 + lo) * 16);
#pragma unroll
                for (int s = 0; s < 2; s++)
#pragma unroll
                    for (int t = 0; t < 2; t++)
                        acc[s][t] = __builtin_amdgcn_mfma_f32_32x32x16_bf16(a[s], b[t], acc[s][t], 0, 0, 0);
            }
        }
    }

    // epilogue: dequant + bias + qrelu -> bytes, transpose via LDS, masked contiguous store
    float inv_s = fmaxf(__uint_as_float(maxw[0]), 1e-8f) / 127.0f;
    __syncthreads();
    char* Cs = lds;                           // [128 q][148]
#pragma unroll
    for (int s = 0; s < 2; s++)
#pragma unroll
        for (int t = 0; t < 2; t++) {
            int qloc = wn * 64 + t * 32 + lo;
#pragma unroll
            for (int reg = 0; reg < 16; reg++) {
                int m = wm * 64 + s * 32 + (reg & 3) + 8 * (reg >> 2) + 4 * hi;
                float val = fmaf(acc[s][t][reg], inv_s, bq1[m]);
                val = fminf(fmaxf(val, 0.f), ALPHA_F);
                int k1 = (int)rintf(val * ARELU_S);
                Cs[qloc * 148 + m] = (char)(k1 - 128);
            }
        }
    __syncthreads();
    char* dst = act1q + (size_t)n * IMGSTRIDE + (size_t)q0 * 16;
#pragma unroll
    for (int it = 0; it < 4; it++) {
        int idx = it * 256 + tid;             // 0..1023 -> (q, cb)
        int ql = idx >> 3, cb = idx & 7;
        int q = q0 + ql;
        int y = q / W58, xx = q - y * W58;
        if ((unsigned)(y - 1) < 56u && (unsigned)(xx - 1) < 56u) {
            int4 w;
            w.x = *(const int*)(Cs + ql * 148 + cb * 16 + 0);
            w.y = *(const int*)(Cs + ql * 148 + cb * 16 + 4);
            w.z = *(const int*)(Cs + ql * 148 + cb * 16 + 8);
            w.w = *(const int*)(Cs + ql * 148 + cb * 16 + 12);
            *(int4*)(dst + (size_t)cb * CBSTRIDE + ql * 16) = w;
        }
    }
}

// ---------------- conv2: 3x3 pad1 i8 MFMA implicit GEMM + qrelu -> i8 ----------------
__global__ __launch_bounds__(256) void conv2_i8_kernel(
    const char* __restrict__ actq, const char* __restrict__ wq2i,
    const int* __restrict__ Q2, const float* __restrict__ bq2,
    const unsigned int* __restrict__ maxw, char* __restrict__ act2q)
{
    __shared__ char lds[48128];
    char* As2 = lds;            // [8 cb][128 m][16]
    char* Bs  = lds + 16384;    // [8 cb][BSROW q][16]
    const int tid = threadIdx.x;
    const int n  = blockIdx.z;
    const int q0 = blockIdx.x * 128;
    const int lane = tid & 63, wid = tid >> 6;
    const int lo = lane & 31, hi = lane >> 5;
    const int wm = wid >> 1, wn = wid & 1;

    // stage B halo: rows q0-59 .. q0+186, all 8 cb planes (guards cover under/overflow)
    const char* src = actq + (size_t)n * IMGSTRIDE + (long)(q0 - 59) * 16;
#pragma unroll
    for (int cb = 0; cb < 8; cb++) {
        if (tid < 246)
            async16(src + (size_t)cb * CBSTRIDE + tid * 16, Bs + cb * (BSROW * 16) + tid * 16);
    }

    // weight-staging addressing: thread -> (m = tid>>1, half = tid&1)
    const int sm = tid >> 1, shalf = tid & 1;
    const char* wsrc = wq2i + sm * CMID + shalf * 64;
    char* wdst = As2 + (shalf * 4) * 2048 + sm * 16;   // ((half*4+i)*128 + m)*16
    int4 pre[4];
#pragma unroll
    for (int i = 0; i < 4; i++) pre[i] = *(const int4*)(wsrc + i * 16);

    v16i acc[2][2] = {};

    for (int tap = 0; tap < 9; tap++) {
        __syncthreads();                      // prior tap's As reads done (and B DMA drained, 1st iter)
        int4 cur[4];
#pragma unroll
        for (int i = 0; i < 4; i++) cur[i] = pre[i];
        if (tap < 8) {
            const char* ns = wsrc + (size_t)(tap + 1) * (CMID * CMID);
#pragma unroll
            for (int i = 0; i < 4; i++) pre[i] = *(const int4*)(ns + i * 16);
        }
#pragma unroll
        for (int i = 0; i < 4; i++) *(int4*)(wdst + i * 2048) = cur[i];
        __syncthreads();                      // As for this tap visible

        const int tapoff = ((tap / 3) - 1) * W58 + (tap % 3) - 1;
#pragma unroll
        for (int ks = 0; ks < 4; ks++) {
            v4i a[2], b[2];
#pragma unroll
            for (int s = 0; s < 2; s++)
                a[s] = *(const v4i*)(As2 + ((ks * 2 + hi) * 128 + wm * 64 + s * 32 + lo) * 16);
#pragma unroll
            for (int t = 0; t < 2; t++) {
                int ql = 59 + tapoff + wn * 64 + t * 32 + lo;
                b[t] = *(const v4i*)(Bs + ((ks * 2 + hi) * BSROW + ql) * 16);
            }
#pragma unroll
            for (int s = 0; s < 2; s++)
#pragma unroll
                for (int t = 0; t < 2; t++)
                    acc[s][t] = __builtin_amdgcn_mfma_i32_32x32x32_i8(a[s], b[t], acc[s][t], 0, 0, 0);
        }
    }

    // epilogue: dequant + qrelu -> bytes, transpose via LDS, contiguous store
    float scale = fmaxf(__uint_as_float(maxw[1]), 1e-8f) / (127.0f * ARELU_S);
    __syncthreads();
    char* Cs = lds;                           // [128 q][148] (pad for bank spread)
#pragma unroll
    for (int s = 0; s < 2; s++)
#pragma unroll
        for (int t = 0; t < 2; t++) {
            int qloc = wn * 64 + t * 32 + lo;
#pragma unroll
            for (int reg = 0; reg < 16; reg++) {
                int m = wm * 64 + s * 32 + (reg & 3) + 8 * (reg >> 2) + 4 * hi;
                float val = fmaf((float)(acc[s][t][reg] + 128 * Q2[m]), scale, bq2[m]);
                val = fminf(fmaxf(val, 0.f), ALPHA_F);
                int k2 = (int)rintf(val * ARELU_S);
                Cs[qloc * 148 + m] = (char)(k2 - 128);
            }
        }
    __syncthreads();
    char* dst = act2q + (size_t)n * IMGSTRIDE + q0 * 16;
#pragma unroll
    for (int it = 0; it < 4; it++) {
        int idx = it * 256 + tid;             // 0..1023 -> (q, cb)
        int q = idx >> 3, cb = idx & 7;
        int4 w;
        w.x = *(const int*)(Cs + q * 148 + cb * 16 + 0);
        w.y = *(const int*)(Cs + q * 148 + cb * 16 + 4);
        w.z = *(const int*)(Cs + q * 148 + cb * 16 + 8);
        w.w = *(const int*)(Cs + q * 148 + cb * 16 + 12);
        *(int4*)(dst + (size_t)cb * CBSTRIDE + q * 16) = w;
    }
}

// ---------------- conv3: 1x1 i8 MFMA GEMM -> fp32 out (masked store) ----------------
__global__ __launch_bounds__(256) void conv3_i8_kernel(
    const char* __restrict__ act2q, const char* __restrict__ wq3i,
    const int* __restrict__ Q3, const float* __restrict__ bq3,
    const unsigned int* __restrict__ maxw, float* __restrict__ out)
{
    __shared__ char lds[32768];
    char* As2 = lds;            // [8 cb][128 m][16]
    char* Bs  = lds + 16384;    // [8 cb][128 q][16]
    const int tid = threadIdx.x;
    const int n  = blockIdx.z;
    const int q0 = blockIdx.x * 128;
    const int m0 = blockIdx.y * 128;
    const int lane = tid & 63, wid = tid >> 6;
    const int lo = lane & 31, hi = lane >> 5;
    const int wm = wid >> 1, wn = wid & 1;

    const char* bsrc = act2q + (size_t)n * IMGSTRIDE + q0 * 16;
#pragma unroll
    for (int i = 0; i < 4; i++) {
        int cb = i * 2 + (tid >> 7), row = tid & 127;
        async16(bsrc + (size_t)cb * CBSTRIDE + row * 16, Bs + cb * 2048 + row * 16);
    }

    const int sm = tid >> 1, shalf = tid & 1;
    const char* wsrc = wq3i + (size_t)(m0 + sm) * CMID + shalf * 64;
    char* wdst = As2 + (shalf * 4) * 2048 + sm * 16;
    int4 w[4];
#pragma unroll
    for (int i = 0; i < 4; i++) w[i] = *(const int4*)(wsrc + i * 16);
#pragma unroll
    for (int i = 0; i < 4; i++) *(int4*)(wdst + i * 2048) = w[i];
    __syncthreads();

    v16i acc[2][2] = {};
#pragma unroll
    for (int ks = 0; ks < 4; ks++) {
        v4i a[2], b[2];
#pragma unroll
        for (int s = 0; s < 2; s++)
            a[s] = *(const v4i*)(As2 + ((ks * 2 + hi) * 128 + wm * 64 + s * 32 + lo) * 16);
#pragma unroll
        for (int t = 0; t < 2; t++)
            b[t] = *(const v4i*)(Bs + ((ks * 2 + hi) * 128 + wn * 64 + t * 32 + lo) * 16);
#pragma unroll
        for (int s = 0; s < 2; s++)
#pragma unroll
            for (int t = 0; t < 2; t++)
                acc[s][t] = __builtin_amdgcn_mfma_i32_32x32x32_i8(a[s], b[t], acc[s][t], 0, 0, 0);
    }

    float scale = fmaxf(__uint_as_float(maxw[2]), 1e-8f) / (127.0f * ARELU_S);
#pragma unroll
    for (int s = 0; s < 2; s++)
#pragma unroll
        for (int t = 0; t < 2; t++) {
            int q = q0 + wn * 64 + t * 32 + lo;
            int y = q / W58, x = q - y * W58;
            if ((unsigned)(y - 1) < 56u && (unsigned)(x - 1) < 56u) {
                int p = (y - 1) * 56 + (x - 1);
                float* op = out + (size_t)n * COUT * HWP + p;
#pragma unroll
                for (int reg = 0; reg < 16; reg++) {
                    int m = m0 + wm * 64 + s * 32 + (reg & 3) + 8 * (reg >> 2) + 4 * hi;
                    op[(size_t)m * HWP] = fmaf((float)(acc[s][t][reg] + 128 * Q3[m]), scale, bq3[m]);
                }
            }
        }
}

extern "C" void kernel_launch(void* const* d_in, const int* in_sizes, int n_in,
                              void* d_out, int out_size, void* d_ws, size_t ws_size,
                              hipStream_t stream) {
    const float* x   = (const float*)d_in[0];
    const float* w1  = (const float*)d_in[1];
    const float* b1  = (const float*)d_in[2];
    const float* g1  = (const float*)d_in[3];
    const float* be1 = (const float*)d_in[4];
    const float* m1  = (const float*)d_in[5];
    const float* v1  = (const float*)d_in[6];
    const float* w2  = (const float*)d_in[7];
    const float* b2  = (const float*)d_in[8];
    const float* g2  = (const float*)d_in[9];
    const float* be2 = (const float*)d_in[10];
    const float* m2  = (const float*)d_in[11];
    const float* v2  = (const float*)d_in[12];
    const float* w3  = (const float*)d_in[13];
    const float* b3  = (const float*)d_in[14];
    const float* g3  = (const float*)d_in[15];
    const float* be3 = (const float*)d_in[16];
    const float* m3  = (const float*)d_in[17];
    const float* v3  = (const float*)d_in[18];

    float* ws  = (float*)d_ws;
    unsigned char* wsb = (unsigned char*)d_ws;
    float* wq1 = ws + OFF_WQ1;
    float* wf2 = ws + OFF_WF2;
    float* wf3 = ws + OFF_WF3;
    float* bq1 = ws + OFF_BQ1;
    float* bq2 = ws + OFF_BQ2;
    float* bq3 = ws + OFF_BQ3;
    unsigned int* maxw = (unsigned int*)(ws + OFF_MAX);
    int* Q2 = (int*)(ws + OFF_Q2);
    int* Q3 = (int*)(ws + OFF_Q3);
    char* wq2i = (char*)(ws + OFF_WQ2I);
    char* wq3i = (char*)(ws + OFF_WQ3I);
    unsigned short* wbf = (unsigned short*)(ws + OFF_WBF1);
    char* act1q = (char*)(wsb + ACT1Q_B);
    char* act2q = (char*)(wsb + ACT2Q_B);
    float* out  = (float*)d_out;

    hipMemsetAsync(maxw, 0, 12, stream);
    // act1 padded planes (+guards) to -128 == pad value (k=0)
    hipMemsetAsync(wsb + ACT1Q_GUARD_B, 0x80, (size_t)GUARD + (size_t)N_IMG * IMGSTRIDE + GUARD, stream);

    fold_max_kernel<<<128, 256, 0, stream>>>(w1, g1, v1, wq1, maxw + 0, CIN,      CMID * CIN);
    fold_max_kernel<<<256, 256, 0, stream>>>(w2, g2, v2, wf2, maxw + 1, CMID * 9, CMID * CMID * 9);
    fold_max_kernel<<<256, 256, 0, stream>>>(w3, g3, v3, wf3, maxw + 2, CMID,     COUT * CMID);

    quant_w1_bf16_kernel<<<128, 256, 0, stream>>>(wq1, maxw + 0, wbf);
    quant_w2_kernel<<<CMID, 256, 0, stream>>>(wf2, maxw, wq2i, Q2);
    quant_w3_kernel<<<COUT, 128, 0, stream>>>(wf3, maxw, wq3i, Q3);

    fold_bias_kernel<<<1, 512, 0, stream>>>(b1, g1, be1, m1, v1, bq1, CMID);
    fold_bias_kernel<<<1, 512, 0, stream>>>(b2, g2, be2, m2, v2, bq2, CMID);
    fold_bias_kernel<<<1, 512, 0, stream>>>(b3, g3, be3, m3, v3, bq3, COUT);

    // conv1 (bf16 MFMA, split-fp32) -> act1q directly (repack fused; tile 26 is all-pad, skipped)
    conv1_bf16_kernel<<<dim3(26, 1, 32), 256, 0, stream>>>(x, wbf, maxw, bq1, act1q);
    // conv2 (3x3 i8 MFMA) -> act2q
    conv2_i8_kernel<<<dim3(27, 1, 32), 256, 0, stream>>>(act1q, wq2i, Q2, bq2, maxw, act2q);
    // conv3 (1x1 i8 MFMA) -> out
    conv3_i8_kernel<<<dim3(27, 4, 32), 256, 0, stream>>>(act2q, wq3i, Q3, bq3, maxw, out);
}

// Round 2
// 455.086 us; speedup vs baseline: 1.3513x; 1.1462x over previous
//
#include <hip/hip_runtime.h>
#include <math.h>

typedef int v4i  __attribute__((ext_vector_type(4)));
typedef int v16i __attribute__((ext_vector_type(16)));
typedef short v8s __attribute__((ext_vector_type(8)));
typedef float v16f __attribute__((ext_vector_type(16)));

#define N_IMG 32
#define CIN   256
#define CMID  128
#define COUT  512
#define HWP   3136
#define W58   58
#define PLANE_Q 3456            // 27 tiles of 128
#define CBSTRIDE (PLANE_Q*16)   // 55296 bytes per 16-channel plane
#define IMGSTRIDE (8*CBSTRIDE)  // 442368 bytes per image (128 ch)
#define BSROW 248               // staged halo rows (246 used)
#define GUARD 16384
#define BN_EPS_F 1e-3f
#define ALPHA_F  10.0f
#define ARELU_S  25.5f

// ---------------- workspace layout (float units unless noted) ----------------
#define OFF_WQ1   0            // 32768 fp32 (conv1 folded weights fp32)
#define OFF_WF2   32768        // 147456 fp32 (folded w2, temp)
#define OFF_WF3   180224       // 65536 fp32 (folded w3, temp)
#define OFF_BQ1   245760
#define OFF_BQ2   245888
#define OFF_BQ3   246016
#define OFF_MAX   246528       // 3 uints
#define OFF_Q2    246536       // 128 ints
#define OFF_Q3    246664       // 512 ints
#define OFF_WQ2I  247296       // i8 [9][8 kb][128 m][16] = 147456 B
#define OFF_WQ3I  284160       // i8 [8 kb][512 m][16]    = 65536 B
#define OFF_WBF1  300544       // bf16 [32 kb][128 m][8] = 64 KB
// byte offsets for i8 activation planes:
#define ACT1Q_GUARD_B 52582400u
#define ACT1Q_B       (ACT1Q_GUARD_B + GUARD)
#define ACT2Q_B       (ACT1Q_B + (unsigned)(N_IMG*IMGSTRIDE) + GUARD)

__device__ __forceinline__ void async16(const char* g, char* l) {
    __builtin_amdgcn_global_load_lds((const __attribute__((address_space(1))) void*)g,
                                     (__attribute__((address_space(3))) void*)l, 16, 0, 0);
}

// ---------------- fused: fold BN into weights + |max| (blocks 0..959), fold+quant bias (960..962) ----
__global__ __launch_bounds__(256) void fold_all_kernel(
    const float* __restrict__ w1, const float* __restrict__ g1, const float* __restrict__ v1,
    const float* __restrict__ w2, const float* __restrict__ g2, const float* __restrict__ v2,
    const float* __restrict__ w3, const float* __restrict__ g3, const float* __restrict__ v3,
    const float* __restrict__ b1, const float* __restrict__ be1, const float* __restrict__ m1,
    const float* __restrict__ b2, const float* __restrict__ be2, const float* __restrict__ m2,
    const float* __restrict__ b3, const float* __restrict__ be3, const float* __restrict__ m3,
    float* __restrict__ wq1, float* __restrict__ wf2, float* __restrict__ wf3,
    float* __restrict__ bq1, float* __restrict__ bq2, float* __restrict__ bq3,
    unsigned int* __restrict__ maxw)
{
    __shared__ float red[256];
    const int b = blockIdx.x, t = threadIdx.x;
    if (b < 960) {
        const float *w, *g, *v; float* wf; int inner; unsigned int* mslot; int i;
        if (b < 128)      { w = w1; g = g1; v = v1; wf = wq1; inner = CIN;      mslot = maxw + 0; i = b * 256 + t; }
        else if (b < 704) { w = w2; g = g2; v = v2; wf = wf2; inner = CMID * 9; mslot = maxw + 1; i = (b - 128) * 256 + t; }
        else              { w = w3; g = g3; v = v3; wf = wf3; inner = CMID;     mslot = maxw + 2; i = (b - 704) * 256 + t; }
        int o = i / inner;
        float sc = g[o] / sqrtf(v[o] + BN_EPS_F);
        float val = w[i] * sc;
        wf[i] = val;
        red[t] = fabsf(val);
        __syncthreads();
        for (int s = 128; s > 0; s >>= 1) {
            if (t < s) red[t] = fmaxf(red[t], red[t + s]);
            __syncthreads();
        }
        if (t == 0) atomicMax(mslot, __float_as_uint(red[0]));
    } else {
        const float *bb, *gg, *bebe, *mm, *vv; float* bq; int nn;
        if (b == 960)      { bb = b1; gg = g1; bebe = be1; mm = m1; vv = v1; bq = bq1; nn = CMID; }
        else if (b == 961) { bb = b2; gg = g2; bebe = be2; mm = m2; vv = v2; bq = bq2; nn = CMID; }
        else               { bb = b3; gg = g3; bebe = be3; mm = m3; vv = v3; bq = bq3; nn = COUT; }
        float val0 = 0.f, val1 = 0.f;
        if (t < nn) {
            float sc = gg[t] / sqrtf(vv[t] + BN_EPS_F);
            val0 = (bb[t] - mm[t]) * sc + bebe[t];
        }
        int t2 = t + 256;
        if (t2 < nn) {
            float sc = gg[t2] / sqrtf(vv[t2] + BN_EPS_F);
            val1 = (bb[t2] - mm[t2]) * sc + bebe[t2];
        }
        red[t] = fmaxf(fabsf(val0), fabsf(val1));
        __syncthreads();
        for (int s = 128; s > 0; s >>= 1) {
            if (t < s) red[t] = fmaxf(red[t], red[t + s]);
            __syncthreads();
        }
        float mx = fmaxf(red[0], 1e-8f);
        float s = 32767.0f / mx;
        if (t < nn)  bq[t]  = rintf(val0 * s) / s;
        if (t2 < nn) bq[t2] = rintf(val1 * s) / s;
    }
}

// ---------------- fused quantization: w1->bf16 (0..127), w2->i8 (128..255), w3->i8 (256..511) ----
__global__ __launch_bounds__(256) void quant_all_kernel(
    const float* __restrict__ wq1f, const float* __restrict__ wf2, const float* __restrict__ wf3,
    const unsigned int* __restrict__ maxw,
    unsigned short* __restrict__ wbf, char* __restrict__ wq2i, char* __restrict__ wq3i,
    int* __restrict__ Q2, int* __restrict__ Q3)
{
    __shared__ int red[256];
    const int b = blockIdx.x, t = threadIdx.x;
    if (b < 128) {
        int i = b * 256 + t;
        float s = 127.0f / fmaxf(__uint_as_float(maxw[0]), 1e-8f);
        int kb = i >> 10, rem = i & 1023;
        int m = rem >> 3, j = rem & 7;
        int c = kb * 8 + j;
        float k = rintf(wq1f[m * CIN + c] * s);
        wbf[i] = (unsigned short)(__float_as_uint(k) >> 16);
    } else if (b < 256) {
        int m = b - 128;
        float s = 127.0f / fmaxf(__uint_as_float(maxw[1]), 1e-8f);
        int sum = 0;
        for (int idx = t; idx < CMID * 9; idx += 256) {
            int c = idx / 9, tap = idx - c * 9;
            int q = (int)rintf(wf2[(size_t)m * (CMID * 9) + idx] * s);
            wq2i[(size_t)tap * 16384 + (c >> 4) * 2048 + m * 16 + (c & 15)] = (char)q;
            sum += q;
        }
        red[t] = sum;
        __syncthreads();
        for (int st = 128; st > 0; st >>= 1) {
            if (t < st) red[t] += red[t + st];
            __syncthreads();
        }
        if (t == 0) Q2[m] = red[0];
    } else {
        int m = (b - 256) * 2 + (t >> 7), c = t & 127;
        float s = 127.0f / fmaxf(__uint_as_float(maxw[2]), 1e-8f);
        int q = (int)rintf(wf3[(size_t)m * CMID + c] * s);
        wq3i[(size_t)(c >> 4) * 8192 + m * 16 + (c & 15)] = (char)q;
        red[t] = q;
        __syncthreads();
        for (int st = 64; st > 0; st >>= 1) {
            if ((t & 127) < st) red[t] += red[t + st];
            __syncthreads();
        }
        if ((t & 127) == 0) Q3[m] = red[t];
    }
}

// ---------------- conv1: 1x1 bf16 MFMA (exact trunc 3-split) + qrelu -> packed i8 ----------------
// A (integer bf16 weights) read directly from global (coalesced 16B/lane).
// x loaded as float4, split x = h+m+l via mantissa masking (exact), staged to LDS.
// Epilogue writes all 128 q rows: interior = data, border = 0x80 pad (memset eliminated).
__global__ __launch_bounds__(256) void conv1_bf16_kernel(
    const float* __restrict__ X, const unsigned short* __restrict__ Wbf,
    const unsigned int* __restrict__ maxw, const float* __restrict__ bq1,
    char* __restrict__ act1q)
{
    __shared__ char lds[49152];
    char* Bh = lds;             // [8 kb][128 q][16]  x hi
    char* Bm = lds + 16384;     //                    x mid
    char* Bl = lds + 32768;     //                    x lo
    const int tid = threadIdx.x;
    const int n  = blockIdx.z;
    const int q0 = blockIdx.x * 128;
    const int lane = tid & 63, wid = tid >> 6;
    const int lo = lane & 31, hi = lane >> 5;
    const int wm = wid >> 1, wn = wid & 1;
    const float* Xn = X + (size_t)n * CIN * HWP;

    // staging: thread -> (kb = tid>>5, q-quad = tid&31), 8 channels x 4 q per chunk
    const int skb = tid >> 5, sqq = tid & 31;
    const int qq0 = q0 + sqq * 4;
    int p_[4];
#pragma unroll
    for (int e = 0; e < 4; e++) {
        int q = qq0 + e;
        int y = q / W58, xx = q - y * W58;
        int p = (y - 1) * 56 + (xx - 1);
        p_[e] = p < 0 ? 0 : (p > HWP - 1 ? HWP - 1 : p);
    }
    const bool fast = (p_[1] == p_[0] + 1) && (p_[2] == p_[0] + 2) && (p_[3] == p_[0] + 3);

    v16f acc[2][2] = {};

    for (int kc = 0; kc < 4; kc++) {          // 4 chunks of 64 input channels
        __syncthreads();                      // prior chunk's LDS reads done
        const float* chbase = Xn + (size_t)(kc * 64 + skb * 8) * HWP;
        float v[8][4];
#pragma unroll
        for (int j = 0; j < 8; j++) {
            const float* cp = chbase + (size_t)j * HWP;
            if (fast) {
                float4 f = *(const float4*)(cp + p_[0]);
                v[j][0] = f.x; v[j][1] = f.y; v[j][2] = f.z; v[j][3] = f.w;
            } else {
#pragma unroll
                for (int e = 0; e < 4; e++) v[j][e] = cp[p_[e]];
            }
        }
#pragma unroll
        for (int e = 0; e < 4; e++) {
            unsigned ph[4], pm_[4], pl[4];
#pragma unroll
            for (int jj = 0; jj < 4; jj++) {
                float a0 = v[2 * jj][e], a1 = v[2 * jj + 1][e];
                unsigned u0 = __float_as_uint(a0), u1 = __float_as_uint(a1);
                unsigned h0 = u0 & 0xFFFF0000u, h1 = u1 & 0xFFFF0000u;
                float r0 = a0 - __uint_as_float(h0), r1 = a1 - __uint_as_float(h1);
                unsigned w0 = __float_as_uint(r0) & 0xFFFF0000u;
                unsigned w1 = __float_as_uint(r1) & 0xFFFF0000u;
                float s0 = r0 - __uint_as_float(w0), s1 = r1 - __uint_as_float(w1);
                unsigned l0 = __float_as_uint(s0) & 0xFFFF0000u;
                unsigned l1 = __float_as_uint(s1) & 0xFFFF0000u;
                ph[jj]  = (h0 >> 16) | h1;
                pm_[jj] = (w0 >> 16) | w1;
                pl[jj]  = (l0 >> 16) | l1;
            }
            int off = (skb * 128 + sqq * 4 + e) * 16;
            *(uint4*)(Bh + off) = make_uint4(ph[0], ph[1], ph[2], ph[3]);
            *(uint4*)(Bm + off) = make_uint4(pm_[0], pm_[1], pm_[2], pm_[3]);
            *(uint4*)(Bl + off) = make_uint4(pl[0], pl[1], pl[2], pl[3]);
        }
        __syncthreads();                      // staging visible

        const char* wbase = (const char*)Wbf + kc * 16384;
#pragma unroll
        for (int ks = 0; ks < 4; ks++) {
            v8s a[2];
#pragma unroll
            for (int s = 0; s < 2; s++)
                a[s] = *(const v8s*)(wbase + (((ks * 2 + hi) * 128) + wm * 64 + s * 32 + lo) * 16);
#pragma unroll
            for (int pass = 0; pass < 3; pass++) {
                const char* Bp = (pass == 0) ? Bh : ((pass == 1) ? Bm : Bl);
                v8s b[2];
#pragma unroll
                for (int t = 0; t < 2; t++)
                    b[t] = *(const v8s*)(Bp + ((ks * 2 + hi) * 128 + wn * 64 + t * 32 + lo) * 16);
#pragma unroll
                for (int s = 0; s < 2; s++)
#pragma unroll
                    for (int t = 0; t < 2; t++)
                        acc[s][t] = __builtin_amdgcn_mfma_f32_32x32x16_bf16(a[s], b[t], acc[s][t], 0, 0, 0);
            }
        }
    }

    // epilogue: dequant + bias + qrelu -> bytes, transpose via LDS, full store (pad = 0x80)
    float inv_s = fmaxf(__uint_as_float(maxw[0]), 1e-8f) / 127.0f;
    __syncthreads();
    char* Cs = lds;                           // [128 q][148]
#pragma unroll
    for (int s = 0; s < 2; s++)
#pragma unroll
        for (int t = 0; t < 2; t++) {
            int qloc = wn * 64 + t * 32 + lo;
#pragma unroll
            for (int reg = 0; reg < 16; reg++) {
                int m = wm * 64 + s * 32 + (reg & 3) + 8 * (reg >> 2) + 4 * hi;
                float val = fmaf(acc[s][t][reg], inv_s, bq1[m]);
                val = fminf(fmaxf(val, 0.f), ALPHA_F);
                int k1 = (int)rintf(val * ARELU_S);
                Cs[qloc * 148 + m] = (char)(k1 - 128);
            }
        }
    __syncthreads();
    char* dst = act1q + (size_t)n * IMGSTRIDE + (size_t)q0 * 16;
#pragma unroll
    for (int it = 0; it < 4; it++) {
        int idx = it * 256 + tid;             // 0..1023 -> (q, cb)
        int ql = idx >> 3, cb = idx & 7;
        int q = q0 + ql;
        int y = q / W58, xx = q - y * W58;
        int4 w;
        if ((unsigned)(y - 1) < 56u && (unsigned)(xx - 1) < 56u) {
            w.x = *(const int*)(Cs + ql * 148 + cb * 16 + 0);
            w.y = *(const int*)(Cs + ql * 148 + cb * 16 + 4);
            w.z = *(const int*)(Cs + ql * 148 + cb * 16 + 8);
            w.w = *(const int*)(Cs + ql * 148 + cb * 16 + 12);
        } else {
            w = make_int4(0x80808080, 0x80808080, 0x80808080, 0x80808080);
        }
        *(int4*)(dst + (size_t)cb * CBSTRIDE + ql * 16) = w;
    }
}

// ---------------- conv2: 3x3 pad1 i8 MFMA implicit GEMM + qrelu -> i8 ----------------
// Weights read directly from global ([tap][kb][m][16] layout, coalesced 16B/lane):
// no A staging, no per-tap barriers.
__global__ __launch_bounds__(256) void conv2_i8_kernel(
    const char* __restrict__ actq, const char* __restrict__ wq2i,
    const int* __restrict__ Q2, const float* __restrict__ bq2,
    const unsigned int* __restrict__ maxw, char* __restrict__ act2q)
{
    __shared__ char lds[31744];
    char* Bs = lds;             // [8 cb][BSROW q][16]
    const int tid = threadIdx.x;
    const int n  = blockIdx.z;
    const int q0 = blockIdx.x * 128;
    const int lane = tid & 63, wid = tid >> 6;
    const int lo = lane & 31, hi = lane >> 5;
    const int wm = wid >> 1, wn = wid & 1;

    // stage B halo: rows q0-59 .. q0+186, all 8 cb planes (guards cover under/overflow)
    const char* src = actq + (size_t)n * IMGSTRIDE + (long)(q0 - 59) * 16;
#pragma unroll
    for (int cb = 0; cb < 8; cb++) {
        if (tid < 246)
            async16(src + (size_t)cb * CBSTRIDE + tid * 16, Bs + cb * (BSROW * 16) + tid * 16);
    }
    __syncthreads();                          // B staged (barrier drains LDS-DMA)

    v16i acc[2][2] = {};
    for (int tap = 0; tap < 9; tap++) {
        const char* wt = wq2i + (size_t)tap * 16384;
        const int tapoff = ((tap / 3) - 1) * W58 + (tap % 3) - 1;
#pragma unroll
        for (int ks = 0; ks < 4; ks++) {
            v4i a[2], b[2];
#pragma unroll
            for (int s = 0; s < 2; s++)
                a[s] = *(const v4i*)(wt + (ks * 2 + hi) * 2048 + (wm * 64 + s * 32 + lo) * 16);
#pragma unroll
            for (int t = 0; t < 2; t++) {
                int ql = 59 + tapoff + wn * 64 + t * 32 + lo;
                b[t] = *(const v4i*)(Bs + ((ks * 2 + hi) * BSROW + ql) * 16);
            }
#pragma unroll
            for (int s = 0; s < 2; s++)
#pragma unroll
                for (int t = 0; t < 2; t++)
                    acc[s][t] = __builtin_amdgcn_mfma_i32_32x32x32_i8(a[s], b[t], acc[s][t], 0, 0, 0);
        }
    }

    // epilogue: dequant + qrelu -> bytes, transpose via LDS, contiguous store
    float scale = fmaxf(__uint_as_float(maxw[1]), 1e-8f) / (127.0f * ARELU_S);
    __syncthreads();
    char* Cs = lds;                           // [128 q][148]
#pragma unroll
    for (int s = 0; s < 2; s++)
#pragma unroll
        for (int t = 0; t < 2; t++) {
            int qloc = wn * 64 + t * 32 + lo;
#pragma unroll
            for (int reg = 0; reg < 16; reg++) {
                int m = wm * 64 + s * 32 + (reg & 3) + 8 * (reg >> 2) + 4 * hi;
                float val = fmaf((float)(acc[s][t][reg] + 128 * Q2[m]), scale, bq2[m]);
                val = fminf(fmaxf(val, 0.f), ALPHA_F);
                int k2 = (int)rintf(val * ARELU_S);
                Cs[qloc * 148 + m] = (char)(k2 - 128);
            }
        }
    __syncthreads();
    char* dst = act2q + (size_t)n * IMGSTRIDE + q0 * 16;
#pragma unroll
    for (int it = 0; it < 4; it++) {
        int idx = it * 256 + tid;             // 0..1023 -> (q, cb)
        int q = idx >> 3, cb = idx & 7;
        int4 w;
        w.x = *(const int*)(Cs + q * 148 + cb * 16 + 0);
        w.y = *(const int*)(Cs + q * 148 + cb * 16 + 4);
        w.z = *(const int*)(Cs + q * 148 + cb * 16 + 8);
        w.w = *(const int*)(Cs + q * 148 + cb * 16 + 12);
        *(int4*)(dst + (size_t)cb * CBSTRIDE + q * 16) = w;
    }
}

// ---------------- conv3: 1x1 i8 MFMA GEMM -> fp32 out (masked store) ----------------
// Weights direct from global ([kb][m][16] layout).
__global__ __launch_bounds__(256) void conv3_i8_kernel(
    const char* __restrict__ act2q, const char* __restrict__ wq3i,
    const int* __restrict__ Q3, const float* __restrict__ bq3,
    const unsigned int* __restrict__ maxw, float* __restrict__ out)
{
    __shared__ char lds[16384];
    char* Bs = lds;             // [8 cb][128 q][16]
    const int tid = threadIdx.x;
    const int n  = blockIdx.z;
    const int q0 = blockIdx.x * 128;
    const int m0 = blockIdx.y * 128;
    const int lane = tid & 63, wid = tid >> 6;
    const int lo = lane & 31, hi = lane >> 5;
    const int wm = wid >> 1, wn = wid & 1;

    const char* bsrc = act2q + (size_t)n * IMGSTRIDE + q0 * 16;
#pragma unroll
    for (int i = 0; i < 4; i++) {
        int cb = i * 2 + (tid >> 7), row = tid & 127;
        async16(bsrc + (size_t)cb * CBSTRIDE + row * 16, Bs + cb * 2048 + row * 16);
    }
    __syncthreads();

    v16i acc[2][2] = {};
#pragma unroll
    for (int ks = 0; ks < 4; ks++) {
        v4i a[2], b[2];
#pragma unroll
        for (int s = 0; s < 2; s++)
            a[s] = *(const v4i*)(wq3i + (ks * 2 + hi) * 8192 + (m0 + wm * 64 + s * 32 + lo) * 16);
#pragma unroll
        for (int t = 0; t < 2; t++)
            b[t] = *(const v4i*)(Bs + ((ks * 2 + hi) * 128 + wn * 64 + t * 32 + lo) * 16);
#pragma unroll
        for (int s = 0; s < 2; s++)
#pragma unroll
            for (int t = 0; t < 2; t++)
                acc[s][t] = __builtin_amdgcn_mfma_i32_32x32x32_i8(a[s], b[t], acc[s][t], 0, 0, 0);
    }

    float scale = fmaxf(__uint_as_float(maxw[2]), 1e-8f) / (127.0f * ARELU_S);
#pragma unroll
    for (int s = 0; s < 2; s++)
#pragma unroll
        for (int t = 0; t < 2; t++) {
            int q = q0 + wn * 64 + t * 32 + lo;
            int y = q / W58, x = q - y * W58;
            if ((unsigned)(y - 1) < 56u && (unsigned)(x - 1) < 56u) {
                int p = (y - 1) * 56 + (x - 1);
                float* op = out + (size_t)n * COUT * HWP + p;
#pragma unroll
                for (int reg = 0; reg < 16; reg++) {
                    int m = m0 + wm * 64 + s * 32 + (reg & 3) + 8 * (reg >> 2) + 4 * hi;
                    op[(size_t)m * HWP] = fmaf((float)(acc[s][t][reg] + 128 * Q3[m]), scale, bq3[m]);
                }
            }
        }
}

extern "C" void kernel_launch(void* const* d_in, const int* in_sizes, int n_in,
                              void* d_out, int out_size, void* d_ws, size_t ws_size,
                              hipStream_t stream) {
    const float* x   = (const float*)d_in[0];
    const float* w1  = (const float*)d_in[1];
    const float* b1  = (const float*)d_in[2];
    const float* g1  = (const float*)d_in[3];
    const float* be1 = (const float*)d_in[4];
    const float* m1  = (const float*)d_in[5];
    const float* v1  = (const float*)d_in[6];
    const float* w2  = (const float*)d_in[7];
    const float* b2  = (const float*)d_in[8];
    const float* g2  = (const float*)d_in[9];
    const float* be2 = (const float*)d_in[10];
    const float* m2  = (const float*)d_in[11];
    const float* v2  = (const float*)d_in[12];
    const float* w3  = (const float*)d_in[13];
    const float* b3  = (const float*)d_in[14];
    const float* g3  = (const float*)d_in[15];
    const float* be3 = (const float*)d_in[16];
    const float* m3  = (const float*)d_in[17];
    const float* v3  = (const float*)d_in[18];

    float* ws  = (float*)d_ws;
    unsigned char* wsb = (unsigned char*)d_ws;
    float* wq1 = ws + OFF_WQ1;
    float* wf2 = ws + OFF_WF2;
    float* wf3 = ws + OFF_WF3;
    float* bq1 = ws + OFF_BQ1;
    float* bq2 = ws + OFF_BQ2;
    float* bq3 = ws + OFF_BQ3;
    unsigned int* maxw = (unsigned int*)(ws + OFF_MAX);
    int* Q2 = (int*)(ws + OFF_Q2);
    int* Q3 = (int*)(ws + OFF_Q3);
    char* wq2i = (char*)(ws + OFF_WQ2I);
    char* wq3i = (char*)(ws + OFF_WQ3I);
    unsigned short* wbf = (unsigned short*)(ws + OFF_WBF1);
    char* act1q = (char*)(wsb + ACT1Q_B);
    char* act2q = (char*)(wsb + ACT2Q_B);
    float* out  = (float*)d_out;

    hipMemsetAsync(maxw, 0, 12, stream);

    fold_all_kernel<<<963, 256, 0, stream>>>(
        w1, g1, v1, w2, g2, v2, w3, g3, v3,
        b1, be1, m1, b2, be2, m2, b3, be3, m3,
        wq1, wf2, wf3, bq1, bq2, bq3, maxw);

    quant_all_kernel<<<512, 256, 0, stream>>>(wq1, wf2, wf3, maxw, wbf, wq2i, wq3i, Q2, Q3);

    // conv1 (bf16 MFMA, exact split) -> act1q directly, pad rows written in-kernel
    conv1_bf16_kernel<<<dim3(27, 1, 32), 256, 0, stream>>>(x, wbf, maxw, bq1, act1q);
    // conv2 (3x3 i8 MFMA) -> act2q
    conv2_i8_kernel<<<dim3(27, 1, 32), 256, 0, stream>>>(act1q, wq2i, Q2, bq2, maxw, act2q);
    // conv3 (1x1 i8 MFMA) -> out
    conv3_i8_kernel<<<dim3(27, 4, 32), 256, 0, stream>>>(act2q, wq3i, Q3, bq3, maxw, out);
}

// Round 3
// 445.027 us; speedup vs baseline: 1.3819x; 1.0226x over previous
//
#include <hip/hip_runtime.h>
#include <math.h>

typedef int v4i  __attribute__((ext_vector_type(4)));
typedef int v16i __attribute__((ext_vector_type(16)));
typedef short v8s __attribute__((ext_vector_type(8)));
typedef float v16f __attribute__((ext_vector_type(16)));

#define N_IMG 32
#define CIN   256
#define CMID  128
#define COUT  512
#define HWP   3136
#define W58   58
#define PLANE_Q 3456            // 27 tiles of 128
#define CBSTRIDE (PLANE_Q*16)   // 55296 bytes per 16-channel plane
#define IMGSTRIDE (8*CBSTRIDE)  // 442368 bytes per image (128 ch)
#define BSROW 248               // staged halo rows (246 used)
#define GUARD 16384
#define BN_EPS_F 1e-3f
#define ALPHA_F  10.0f
#define ARELU_S  25.5f

// ---------------- workspace layout (float units unless noted) ----------------
#define OFF_WQ1   0            // 32768 fp32 (conv1 folded weights fp32)
#define OFF_WF2   32768        // 147456 fp32 (folded w2, temp)
#define OFF_WF3   180224       // 65536 fp32 (folded w3, temp)
#define OFF_BQ1   245760
#define OFF_BQ2   245888
#define OFF_BQ3   246016
#define OFF_MAX   246528       // 3 uints
#define OFF_Q2    246536       // 128 ints
#define OFF_Q3    246664       // 512 ints
#define OFF_WQ2I  247296       // i8 [9][8 kb][128 m][16] = 147456 B
#define OFF_WQ3I  284160       // i8 [8 kb][512 m][16]    = 65536 B
#define OFF_WBF1  300544       // bf16 [32 kb][128 m][8] = 64 KB
// byte offsets for i8 activation planes:
#define ACT1Q_GUARD_B 52582400u
#define ACT1Q_B       (ACT1Q_GUARD_B + GUARD)

__device__ __forceinline__ void async16(const char* g, char* l) {
    __builtin_amdgcn_global_load_lds((const __attribute__((address_space(1))) void*)g,
                                     (__attribute__((address_space(3))) void*)l, 16, 0, 0);
}

// ---------------- fused: fold BN into weights + |max| (blocks 0..959), fold+quant bias (960..962) ----
__global__ __launch_bounds__(256) void fold_all_kernel(
    const float* __restrict__ w1, const float* __restrict__ g1, const float* __restrict__ v1,
    const float* __restrict__ w2, const float* __restrict__ g2, const float* __restrict__ v2,
    const float* __restrict__ w3, const float* __restrict__ g3, const float* __restrict__ v3,
    const float* __restrict__ b1, const float* __restrict__ be1, const float* __restrict__ m1,
    const float* __restrict__ b2, const float* __restrict__ be2, const float* __restrict__ m2,
    const float* __restrict__ b3, const float* __restrict__ be3, const float* __restrict__ m3,
    float* __restrict__ wq1, float* __restrict__ wf2, float* __restrict__ wf3,
    float* __restrict__ bq1, float* __restrict__ bq2, float* __restrict__ bq3,
    unsigned int* __restrict__ maxw)
{
    __shared__ float red[256];
    const int b = blockIdx.x, t = threadIdx.x;
    if (b < 960) {
        const float *w, *g, *v; float* wf; int inner; unsigned int* mslot; int i;
        if (b < 128)      { w = w1; g = g1; v = v1; wf = wq1; inner = CIN;      mslot = maxw + 0; i = b * 256 + t; }
        else if (b < 704) { w = w2; g = g2; v = v2; wf = wf2; inner = CMID * 9; mslot = maxw + 1; i = (b - 128) * 256 + t; }
        else              { w = w3; g = g3; v = v3; wf = wf3; inner = CMID;     mslot = maxw + 2; i = (b - 704) * 256 + t; }
        int o = i / inner;
        float sc = g[o] / sqrtf(v[o] + BN_EPS_F);
        float val = w[i] * sc;
        wf[i] = val;
        red[t] = fabsf(val);
        __syncthreads();
        for (int s = 128; s > 0; s >>= 1) {
            if (t < s) red[t] = fmaxf(red[t], red[t + s]);
            __syncthreads();
        }
        if (t == 0) atomicMax(mslot, __float_as_uint(red[0]));
    } else {
        const float *bb, *gg, *bebe, *mm, *vv; float* bq; int nn;
        if (b == 960)      { bb = b1; gg = g1; bebe = be1; mm = m1; vv = v1; bq = bq1; nn = CMID; }
        else if (b == 961) { bb = b2; gg = g2; bebe = be2; mm = m2; vv = v2; bq = bq2; nn = CMID; }
        else               { bb = b3; gg = g3; bebe = be3; mm = m3; vv = v3; bq = bq3; nn = COUT; }
        float val0 = 0.f, val1 = 0.f;
        if (t < nn) {
            float sc = gg[t] / sqrtf(vv[t] + BN_EPS_F);
            val0 = (bb[t] - mm[t]) * sc + bebe[t];
        }
        int t2 = t + 256;
        if (t2 < nn) {
            float sc = gg[t2] / sqrtf(vv[t2] + BN_EPS_F);
            val1 = (bb[t2] - mm[t2]) * sc + bebe[t2];
        }
        red[t] = fmaxf(fabsf(val0), fabsf(val1));
        __syncthreads();
        for (int s = 128; s > 0; s >>= 1) {
            if (t < s) red[t] = fmaxf(red[t], red[t + s]);
            __syncthreads();
        }
        float mx = fmaxf(red[0], 1e-8f);
        float s = 32767.0f / mx;
        if (t < nn)  bq[t]  = rintf(val0 * s) / s;
        if (t2 < nn) bq[t2] = rintf(val1 * s) / s;
    }
}

// ---------------- fused quantization: w1->bf16 (0..127), w2->i8 (128..255), w3->i8 (256..511) ----
__global__ __launch_bounds__(256) void quant_all_kernel(
    const float* __restrict__ wq1f, const float* __restrict__ wf2, const float* __restrict__ wf3,
    const unsigned int* __restrict__ maxw,
    unsigned short* __restrict__ wbf, char* __restrict__ wq2i, char* __restrict__ wq3i,
    int* __restrict__ Q2, int* __restrict__ Q3)
{
    __shared__ int red[256];
    const int b = blockIdx.x, t = threadIdx.x;
    if (b < 128) {
        int i = b * 256 + t;
        float s = 127.0f / fmaxf(__uint_as_float(maxw[0]), 1e-8f);
        int kb = i >> 10, rem = i & 1023;
        int m = rem >> 3, j = rem & 7;
        int c = kb * 8 + j;
        float k = rintf(wq1f[m * CIN + c] * s);
        wbf[i] = (unsigned short)(__float_as_uint(k) >> 16);
    } else if (b < 256) {
        int m = b - 128;
        float s = 127.0f / fmaxf(__uint_as_float(maxw[1]), 1e-8f);
        int sum = 0;
        for (int idx = t; idx < CMID * 9; idx += 256) {
            int c = idx / 9, tap = idx - c * 9;
            int q = (int)rintf(wf2[(size_t)m * (CMID * 9) + idx] * s);
            wq2i[(size_t)tap * 16384 + (c >> 4) * 2048 + m * 16 + (c & 15)] = (char)q;
            sum += q;
        }
        red[t] = sum;
        __syncthreads();
        for (int st = 128; st > 0; st >>= 1) {
            if (t < st) red[t] += red[t + st];
            __syncthreads();
        }
        if (t == 0) Q2[m] = red[0];
    } else {
        int m = (b - 256) * 2 + (t >> 7), c = t & 127;
        float s = 127.0f / fmaxf(__uint_as_float(maxw[2]), 1e-8f);
        int q = (int)rintf(wf3[(size_t)m * CMID + c] * s);
        wq3i[(size_t)(c >> 4) * 8192 + m * 16 + (c & 15)] = (char)q;
        red[t] = q;
        __syncthreads();
        for (int st = 64; st > 0; st >>= 1) {
            if ((t & 127) < st) red[t] += red[t + st];
            __syncthreads();
        }
        if ((t & 127) == 0) Q3[m] = red[t];
    }
}

// ---------------- conv1: 1x1 bf16 MFMA (exact trunc 3-split) + qrelu -> packed i8 ----------------
__global__ __launch_bounds__(256) void conv1_bf16_kernel(
    const float* __restrict__ X, const unsigned short* __restrict__ Wbf,
    const unsigned int* __restrict__ maxw, const float* __restrict__ bq1,
    char* __restrict__ act1q)
{
    __shared__ char lds[49152];
    char* Bh = lds;             // [8 kb][128 q][16]  x hi
    char* Bm = lds + 16384;     //                    x mid
    char* Bl = lds + 32768;     //                    x lo
    const int tid = threadIdx.x;
    const int n  = blockIdx.z;
    const int q0 = blockIdx.x * 128;
    const int lane = tid & 63, wid = tid >> 6;
    const int lo = lane & 31, hi = lane >> 5;
    const int wm = wid >> 1, wn = wid & 1;
    const float* Xn = X + (size_t)n * CIN * HWP;

    const int skb = tid >> 5, sqq = tid & 31;
    const int qq0 = q0 + sqq * 4;
    int p_[4];
#pragma unroll
    for (int e = 0; e < 4; e++) {
        int q = qq0 + e;
        int y = q / W58, xx = q - y * W58;
        int p = (y - 1) * 56 + (xx - 1);
        p_[e] = p < 0 ? 0 : (p > HWP - 1 ? HWP - 1 : p);
    }
    const bool fast = (p_[1] == p_[0] + 1) && (p_[2] == p_[0] + 2) && (p_[3] == p_[0] + 3);

    v16f acc[2][2] = {};

    for (int kc = 0; kc < 4; kc++) {          // 4 chunks of 64 input channels
        __syncthreads();
        const float* chbase = Xn + (size_t)(kc * 64 + skb * 8) * HWP;
        float v[8][4];
#pragma unroll
        for (int j = 0; j < 8; j++) {
            const float* cp = chbase + (size_t)j * HWP;
            if (fast) {
                float4 f = *(const float4*)(cp + p_[0]);
                v[j][0] = f.x; v[j][1] = f.y; v[j][2] = f.z; v[j][3] = f.w;
            } else {
#pragma unroll
                for (int e = 0; e < 4; e++) v[j][e] = cp[p_[e]];
            }
        }
#pragma unroll
        for (int e = 0; e < 4; e++) {
            unsigned ph[4], pm_[4], pl[4];
#pragma unroll
            for (int jj = 0; jj < 4; jj++) {
                float a0 = v[2 * jj][e], a1 = v[2 * jj + 1][e];
                unsigned u0 = __float_as_uint(a0), u1 = __float_as_uint(a1);
                unsigned h0 = u0 & 0xFFFF0000u, h1 = u1 & 0xFFFF0000u;
                float r0 = a0 - __uint_as_float(h0), r1 = a1 - __uint_as_float(h1);
                unsigned w0 = __float_as_uint(r0) & 0xFFFF0000u;
                unsigned w1 = __float_as_uint(r1) & 0xFFFF0000u;
                float s0 = r0 - __uint_as_float(w0), s1 = r1 - __uint_as_float(w1);
                unsigned l0 = __float_as_uint(s0) & 0xFFFF0000u;
                unsigned l1 = __float_as_uint(s1) & 0xFFFF0000u;
                ph[jj]  = (h0 >> 16) | h1;
                pm_[jj] = (w0 >> 16) | w1;
                pl[jj]  = (l0 >> 16) | l1;
            }
            int off = (skb * 128 + sqq * 4 + e) * 16;
            *(uint4*)(Bh + off) = make_uint4(ph[0], ph[1], ph[2], ph[3]);
            *(uint4*)(Bm + off) = make_uint4(pm_[0], pm_[1], pm_[2], pm_[3]);
            *(uint4*)(Bl + off) = make_uint4(pl[0], pl[1], pl[2], pl[3]);
        }
        __syncthreads();

        const char* wbase = (const char*)Wbf + kc * 16384;
#pragma unroll
        for (int ks = 0; ks < 4; ks++) {
            v8s a[2];
#pragma unroll
            for (int s = 0; s < 2; s++)
                a[s] = *(const v8s*)(wbase + (((ks * 2 + hi) * 128) + wm * 64 + s * 32 + lo) * 16);
#pragma unroll
            for (int pass = 0; pass < 3; pass++) {
                const char* Bp = (pass == 0) ? Bh : ((pass == 1) ? Bm : Bl);
                v8s b[2];
#pragma unroll
                for (int t = 0; t < 2; t++)
                    b[t] = *(const v8s*)(Bp + ((ks * 2 + hi) * 128 + wn * 64 + t * 32 + lo) * 16);
#pragma unroll
                for (int s = 0; s < 2; s++)
#pragma unroll
                    for (int t = 0; t < 2; t++)
                        acc[s][t] = __builtin_amdgcn_mfma_f32_32x32x16_bf16(a[s], b[t], acc[s][t], 0, 0, 0);
            }
        }
    }

    float inv_s = fmaxf(__uint_as_float(maxw[0]), 1e-8f) / 127.0f;
    __syncthreads();
    char* Cs = lds;                           // [128 q][148]
#pragma unroll
    for (int s = 0; s < 2; s++)
#pragma unroll
        for (int t = 0; t < 2; t++) {
            int qloc = wn * 64 + t * 32 + lo;
#pragma unroll
            for (int reg = 0; reg < 16; reg++) {
                int m = wm * 64 + s * 32 + (reg & 3) + 8 * (reg >> 2) + 4 * hi;
                float val = fmaf(acc[s][t][reg], inv_s, bq1[m]);
                val = fminf(fmaxf(val, 0.f), ALPHA_F);
                int k1 = (int)rintf(val * ARELU_S);
                Cs[qloc * 148 + m] = (char)(k1 - 128);
            }
        }
    __syncthreads();
    char* dst = act1q + (size_t)n * IMGSTRIDE + (size_t)q0 * 16;
#pragma unroll
    for (int it = 0; it < 4; it++) {
        int idx = it * 256 + tid;
        int ql = idx >> 3, cb = idx & 7;
        int q = q0 + ql;
        int y = q / W58, xx = q - y * W58;
        int4 w;
        if ((unsigned)(y - 1) < 56u && (unsigned)(xx - 1) < 56u) {
            w.x = *(const int*)(Cs + ql * 148 + cb * 16 + 0);
            w.y = *(const int*)(Cs + ql * 148 + cb * 16 + 4);
            w.z = *(const int*)(Cs + ql * 148 + cb * 16 + 8);
            w.w = *(const int*)(Cs + ql * 148 + cb * 16 + 12);
        } else {
            w = make_int4(0x80808080, 0x80808080, 0x80808080, 0x80808080);
        }
        *(int4*)(dst + (size_t)cb * CBSTRIDE + ql * 16) = w;
    }
}

// ---------------- fused conv2 (3x3 i8 MFMA + qrelu) -> LDS -> conv3 (1x1 i8 MFMA) -> fp32 out ----
// act2q never touches HBM: conv3's q-tile needs exactly conv2's q-tile (no halo).
__global__ __launch_bounds__(256) void conv23_i8_kernel(
    const char* __restrict__ actq, const char* __restrict__ wq2i,
    const char* __restrict__ wq3i,
    const int* __restrict__ Q2, const float* __restrict__ bq2,
    const int* __restrict__ Q3, const float* __restrict__ bq3,
    const unsigned int* __restrict__ maxw, float* __restrict__ out)
{
    __shared__ char lds[48128];
    char* Bs = lds;              // [8 cb][BSROW q][16] act1 halo
    char* Ps = lds + 31744;      // [8 cb][128 q][16] conv2 i8 result
    const int tid = threadIdx.x;
    const int n  = blockIdx.z;
    const int q0 = blockIdx.x * 128;
    const int lane = tid & 63, wid = tid >> 6;
    const int lo = lane & 31, hi = lane >> 5;
    const int wm = wid >> 1, wn = wid & 1;

    // ---- conv2 phase ----
    const char* src = actq + (size_t)n * IMGSTRIDE + (long)(q0 - 59) * 16;
#pragma unroll
    for (int cb = 0; cb < 8; cb++) {
        if (tid < 246)
            async16(src + (size_t)cb * CBSTRIDE + tid * 16, Bs + cb * (BSROW * 16) + tid * 16);
    }
    __syncthreads();                          // B staged (barrier drains LDS-DMA)

    v16i acc[2][2] = {};
    for (int tap = 0; tap < 9; tap++) {
        const char* wt = wq2i + (size_t)tap * 16384;
        const int tapoff = ((tap / 3) - 1) * W58 + (tap % 3) - 1;
#pragma unroll
        for (int ks = 0; ks < 4; ks++) {
            v4i a[2], b[2];
#pragma unroll
            for (int s = 0; s < 2; s++)
                a[s] = *(const v4i*)(wt + (ks * 2 + hi) * 2048 + (wm * 64 + s * 32 + lo) * 16);
#pragma unroll
            for (int t = 0; t < 2; t++) {
                int ql = 59 + tapoff + wn * 64 + t * 32 + lo;
                b[t] = *(const v4i*)(Bs + ((ks * 2 + hi) * BSROW + ql) * 16);
            }
#pragma unroll
            for (int s = 0; s < 2; s++)
#pragma unroll
                for (int t = 0; t < 2; t++)
                    acc[s][t] = __builtin_amdgcn_mfma_i32_32x32x32_i8(a[s], b[t], acc[s][t], 0, 0, 0);
        }
    }

    // qrelu -> bytes into Cs (overlays dead Bs), then repack to Ps [cb][q][16]
    float scale2 = fmaxf(__uint_as_float(maxw[1]), 1e-8f) / (127.0f * ARELU_S);
    __syncthreads();                          // all Bs reads done
    char* Cs = lds;                           // [128 q][148]
#pragma unroll
    for (int s = 0; s < 2; s++)
#pragma unroll
        for (int t = 0; t < 2; t++) {
            int qloc = wn * 64 + t * 32 + lo;
#pragma unroll
            for (int reg = 0; reg < 16; reg++) {
                int m = wm * 64 + s * 32 + (reg & 3) + 8 * (reg >> 2) + 4 * hi;
                float val = fmaf((float)(acc[s][t][reg] + 128 * Q2[m]), scale2, bq2[m]);
                val = fminf(fmaxf(val, 0.f), ALPHA_F);
                int k2 = (int)rintf(val * ARELU_S);
                Cs[qloc * 148 + m] = (char)(k2 - 128);
            }
        }
    __syncthreads();
#pragma unroll
    for (int it = 0; it < 4; it++) {
        int idx = it * 256 + tid;             // 0..1023 -> (cb, q)
        int cb = idx >> 7, q = idx & 127;
        int4 w;
        w.x = *(const int*)(Cs + q * 148 + cb * 16 + 0);
        w.y = *(const int*)(Cs + q * 148 + cb * 16 + 4);
        w.z = *(const int*)(Cs + q * 148 + cb * 16 + 8);
        w.w = *(const int*)(Cs + q * 148 + cb * 16 + 12);
        *(int4*)(Ps + cb * 2048 + q * 16) = w;
    }
    __syncthreads();                          // Ps ready; no more barriers needed

    // ---- conv3 phase ----
    float scale3 = fmaxf(__uint_as_float(maxw[2]), 1e-8f) / (127.0f * ARELU_S);
    // hoist B fragments (reused by all 4 m-blocks)
    v4i bf[4][2];
#pragma unroll
    for (int ks = 0; ks < 4; ks++)
#pragma unroll
        for (int t = 0; t < 2; t++)
            bf[ks][t] = *(const v4i*)(Ps + (ks * 2 + hi) * 2048 + (wn * 64 + t * 32 + lo) * 16);

    const int qq = q0 + wn * 64 + lo;         // t-dependent part added below
#pragma unroll
    for (int m0i = 0; m0i < 4; m0i++) {
        const int m0 = m0i * 128;
        v16i acc3[2][2] = {};
#pragma unroll
        for (int ks = 0; ks < 4; ks++) {
            v4i a[2];
#pragma unroll
            for (int s = 0; s < 2; s++)
                a[s] = *(const v4i*)(wq3i + (ks * 2 + hi) * 8192 + (m0 + wm * 64 + s * 32 + lo) * 16);
#pragma unroll
            for (int s = 0; s < 2; s++)
#pragma unroll
                for (int t = 0; t < 2; t++)
                    acc3[s][t] = __builtin_amdgcn_mfma_i32_32x32x32_i8(a[s], bf[ks][t], acc3[s][t], 0, 0, 0);
        }
#pragma unroll
        for (int s = 0; s < 2; s++)
#pragma unroll
            for (int t = 0; t < 2; t++) {
                int q = qq + t * 32;
                int y = q / W58, x = q - y * W58;
                if ((unsigned)(y - 1) < 56u && (unsigned)(x - 1) < 56u) {
                    int p = (y - 1) * 56 + (x - 1);
                    float* op = out + (size_t)n * COUT * HWP + p;
#pragma unroll
                    for (int reg = 0; reg < 16; reg++) {
                        int m = m0 + wm * 64 + s * 32 + (reg & 3) + 8 * (reg >> 2) + 4 * hi;
                        op[(size_t)m * HWP] = fmaf((float)(acc3[s][t][reg] + 128 * Q3[m]), scale3, bq3[m]);
                    }
                }
            }
    }
}

extern "C" void kernel_launch(void* const* d_in, const int* in_sizes, int n_in,
                              void* d_out, int out_size, void* d_ws, size_t ws_size,
                              hipStream_t stream) {
    const float* x   = (const float*)d_in[0];
    const float* w1  = (const float*)d_in[1];
    const float* b1  = (const float*)d_in[2];
    const float* g1  = (const float*)d_in[3];
    const float* be1 = (const float*)d_in[4];
    const float* m1  = (const float*)d_in[5];
    const float* v1  = (const float*)d_in[6];
    const float* w2  = (const float*)d_in[7];
    const float* b2  = (const float*)d_in[8];
    const float* g2  = (const float*)d_in[9];
    const float* be2 = (const float*)d_in[10];
    const float* m2  = (const float*)d_in[11];
    const float* v2  = (const float*)d_in[12];
    const float* w3  = (const float*)d_in[13];
    const float* b3  = (const float*)d_in[14];
    const float* g3  = (const float*)d_in[15];
    const float* be3 = (const float*)d_in[16];
    const float* m3  = (const float*)d_in[17];
    const float* v3  = (const float*)d_in[18];

    float* ws  = (float*)d_ws;
    unsigned char* wsb = (unsigned char*)d_ws;
    float* wq1 = ws + OFF_WQ1;
    float* wf2 = ws + OFF_WF2;
    float* wf3 = ws + OFF_WF3;
    float* bq1 = ws + OFF_BQ1;
    float* bq2 = ws + OFF_BQ2;
    float* bq3 = ws + OFF_BQ3;
    unsigned int* maxw = (unsigned int*)(ws + OFF_MAX);
    int* Q2 = (int*)(ws + OFF_Q2);
    int* Q3 = (int*)(ws + OFF_Q3);
    char* wq2i = (char*)(ws + OFF_WQ2I);
    char* wq3i = (char*)(ws + OFF_WQ3I);
    unsigned short* wbf = (unsigned short*)(ws + OFF_WBF1);
    char* act1q = (char*)(wsb + ACT1Q_B);
    float* out  = (float*)d_out;

    hipMemsetAsync(maxw, 0, 12, stream);

    fold_all_kernel<<<963, 256, 0, stream>>>(
        w1, g1, v1, w2, g2, v2, w3, g3, v3,
        b1, be1, m1, b2, be2, m2, b3, be3, m3,
        wq1, wf2, wf3, bq1, bq2, bq3, maxw);

    quant_all_kernel<<<512, 256, 0, stream>>>(wq1, wf2, wf3, maxw, wbf, wq2i, wq3i, Q2, Q3);

    // conv1 (bf16 MFMA, exact split) -> act1q, pad rows written in-kernel
    conv1_bf16_kernel<<<dim3(27, 1, 32), 256, 0, stream>>>(x, wbf, maxw, bq1, act1q);
    // fused conv2+conv3: act2 lives only in LDS
    conv23_i8_kernel<<<dim3(27, 1, 32), 256, 0, stream>>>(act1q, wq2i, wq3i, Q2, bq2, Q3, bq3, maxw, out);
}